// Round 9
// baseline (44.078 us; speedup 1.0000x reference)
//
#include <hip/hip_runtime.h>

// Indexed segmented linear, bucketed-by-element grouped GEMM with bf16 MFMA.
//   segments (mi, mo, d): (96,96,1), (64,64,3), (32,32,5)
//   y[b, o*d+m] = sum_i x[b, i*d+m] * W[idx[b], i*mo+o]
//
// Pipeline (3 kernels, no memset):
//   K1 combo (1152x256): blk 0-63    -> per-256-row-chunk histogram of widx
//                        blk 64-127  -> wprep: W -> bf16 transposed
//                                       Wt[e][seg][o][i] (padded) via LDS
//                        blk 128-1151-> xprep: row-ordered de-interleave of x
//                                       into bf16 xs0/xs1/xs2 (row strides
//                                       104/200/168 halves). One row per
//                                       wave; __syncthreads() between the
//                                       LDS write phase and the cross-lane
//                                       permute reads (R8 omitted these ->
//                                       compiler hoisted ds_reads above
//                                       ds_writes -> NaN). Pads zeroed.
//   K2 scatter (64x256): fused scan (per-block bases from hists) -> rowids;
//                        block 0 writes offsets/tileoff/blk2e tables
//   K3 gemm (3*576x256): one block = (segment, 32-row tile). Stage W seg +
//                        x rows as pure uint4 copies (xs pre-formatted),
//                        16x16x32 bf16 MFMA, store f32 via rid_s.

#define BATCH     16384
#define IN_SIZE   448
#define OUT_SIZE  448
#define W_SIZE    14336
#define NELEM     64
#define RTILE     32
#define MAXTILES  576         // >= 512 + 63 worst case
#define WT_ELEM   15872       // halves: 96*104 + 64*72 + 32*40

#define XP0 104               // xs row strides in halves (MI*D + 8)
#define XP1 200
#define XP2 168

typedef __attribute__((ext_vector_type(8))) short short8;
typedef __attribute__((ext_vector_type(4))) float f32x4;

__device__ __forceinline__ unsigned short f2bf(float f) {
    unsigned int u = __float_as_uint(f);
    u += 0x7fffu + ((u >> 16) & 1u);        // round-to-nearest-even
    return (unsigned short)(u >> 16);
}

// ---------------- K1: hist + wprep + xprep ----------------

__device__ __forceinline__ void wprep_seg(const float* __restrict__ we,
                                          unsigned short* __restrict__ de,
                                          unsigned short* lw, int t,
                                          int SRC, int CNT, int MO, int STR,
                                          int DB, int LWS, int MI) {
    for (int g = t; g < CNT; g += 256) {
        const int i = g / MO, o = g - i * MO;
        lw[i * LWS + o] = f2bf(we[SRC + g]);
    }
    __syncthreads();
    const int TOT = MO * STR;
    for (int d = t; d < TOT; d += 256) {
        const int o = d / STR, i = d - o * STR;
        de[DB + d] = (i < MI) ? lw[i * LWS + o] : (unsigned short)0;
    }
    __syncthreads();
}

__global__ __launch_bounds__(256) void combo_kernel(
    const int* __restrict__ widx, const float* __restrict__ weights,
    const float* __restrict__ x,
    int* __restrict__ hists, unsigned short* __restrict__ wt,
    unsigned short* __restrict__ xs0, unsigned short* __restrict__ xs1,
    unsigned short* __restrict__ xs2) {
    __shared__ __align__(16) unsigned short lw[9408];   // wprep 96*98; xprep 4*464
    __shared__ int h[NELEM];
    const int t = threadIdx.x;

    if (blockIdx.x < 64) {                   // ---- hist ----
        if (t < NELEM) h[t] = 0;
        __syncthreads();
        atomicAdd(&h[widx[blockIdx.x * 256 + t]], 1);
        __syncthreads();
        if (t < NELEM) hists[blockIdx.x * NELEM + t] = h[t];
        return;
    }
    if (blockIdx.x < 128) {                  // ---- wprep ----
        const int e = blockIdx.x - 64;
        const float* __restrict__ we = weights + e * W_SIZE;
        unsigned short* __restrict__ de = wt + (size_t)e * WT_ELEM;
        wprep_seg(we, de, lw, t,     0, 9216, 96, 104,     0, 98, 96);
        wprep_seg(we, de, lw, t,  9216, 4096, 64,  72,  9984, 66, 64);
        wprep_seg(we, de, lw, t, 13312, 1024, 32,  40, 14592, 34, 32);
        return;
    }

    // ---- xprep: one row per wave per iteration ----
    const int wv = t >> 6, l = t & 63;
    unsigned short* xb = lw + wv * 464;      // 448 data + 16 pad halves
    const int wid = (blockIdx.x - 128) * 4 + wv;   // 0..4095

    for (int rr = 0; rr < 4; ++rr) {
        const int row = wid * 4 + rr;
        const float* __restrict__ xr = x + (size_t)row * IN_SIZE;
        #pragma unroll
        for (int k = 0; k < 7; ++k)
            xb[k * 64 + l] = f2bf(xr[k * 64 + l]);   // coalesced reads
        __syncthreads();                     // order cross-lane LDS exchange

        const unsigned int* __restrict__ xb32 = (const unsigned int*)xb;
        // seg0: identity copy of halves [0,96) + zeroed pad
        unsigned int* __restrict__ d0 = (unsigned int*)(xs0 + (size_t)row * XP0);
        if (l < 52) d0[l] = (l < 48) ? xb32[l] : 0u;
        // seg1: dst half m*64+i <- src half 96 + 3i + m  (u32 p: m=p>>5, i=2(p&31))
        unsigned int* __restrict__ d1 = (unsigned int*)(xs1 + (size_t)row * XP1);
        #pragma unroll
        for (int p = l; p < 100; p += 64) {
            unsigned int v = 0u;
            if (p < 96) {
                const int s0 = 96 + 6 * (p & 31) + (p >> 5);
                v = (unsigned int)xb[s0] | ((unsigned int)xb[s0 + 3] << 16);
            }
            d1[p] = v;
        }
        // seg2: dst half m*32+i <- src half 288 + 5i + m  (u32 p: m=p>>4, i=2(p&15))
        unsigned int* __restrict__ d2 = (unsigned int*)(xs2 + (size_t)row * XP2);
        #pragma unroll
        for (int p = l; p < 84; p += 64) {
            unsigned int v = 0u;
            if (p < 80) {
                const int s0 = 288 + 10 * (p & 15) + (p >> 4);
                v = (unsigned int)xb[s0] | ((unsigned int)xb[s0 + 5] << 16);
            }
            d2[p] = v;
        }
        __syncthreads();                     // before next row overwrites xb
    }
}

// ---------------- K2: fused scan + scatter (rowids + tables) ----------------

__global__ __launch_bounds__(256) void scatter_kernel(
    const int* __restrict__ widx, const int* __restrict__ hists,
    int* __restrict__ offsets, int* __restrict__ tileoff, int* __restrict__ blk2e,
    int* __restrict__ rowids) {
    __shared__ int tot_s[NELEM], pre_s[NELEM], base_s[NELEM];
    __shared__ int off_s[NELEM + 1], tl_s[NELEM + 1];
    const int b = blockIdx.x, t = threadIdx.x;

    if (t < NELEM) {
        int before = 0, tot = 0;
        for (int c = 0; c < 64; ++c) {
            const int h = hists[c * NELEM + t];
            before += (c < b) ? h : 0;
            tot += h;
        }
        tot_s[t] = tot; pre_s[t] = before;
    }
    __syncthreads();
    if (t == 0) {
        int o = 0, tl = 0;
        for (int e = 0; e < NELEM; ++e) {
            off_s[e] = o; tl_s[e] = tl;
            o += tot_s[e]; tl += (tot_s[e] + RTILE - 1) >> 5;
        }
        off_s[NELEM] = o; tl_s[NELEM] = tl;
    }
    __syncthreads();
    if (t < NELEM) base_s[t] = off_s[t] + pre_s[t];

    if (b == 0) {
        if (t < NELEM) { offsets[t] = off_s[t]; tileoff[t] = tl_s[t]; }
        if (t == 0)    { offsets[NELEM] = off_s[NELEM]; tileoff[NELEM] = tl_s[NELEM]; }
        for (int i = t; i < MAXTILES; i += 256) blk2e[i] = -1;
        __syncthreads();
        if (t < NELEM)
            for (int bb = tl_s[t]; bb < tl_s[t + 1]; ++bb) blk2e[bb] = t;
    }
    __syncthreads();

    const int row = b * 256 + t;
    const int e = widx[row];
    const int pos = atomicAdd(&base_s[e], 1);
    rowids[pos] = row;
}

// ---------------- K3: grouped GEMM, pure uint4 staging ----------------

template <int MI, int MO, int D, int YOFF, int WB>
__device__ __forceinline__ void do_seg(const unsigned short* __restrict__ xs_seg,
                                       const unsigned short* __restrict__ wt_e,
                                       const int* rid_s, int nrows,
                                       float* __restrict__ out,
                                       unsigned short* lds_w, unsigned short* lds_x,
                                       int t) {
    constexpr int XP   = MI * D + 8;         // x row stride (halves)
    constexpr int WSTR = MI + 8;             // W row stride (halves)
    constexpr int NT   = MO / 16;
    constexpr int KB   = MI / 32;
    constexpr int MTL  = 2 * D;
    constexpr int WCH  = (MO * WSTR) / 8;    // 16B chunks of W seg
    constexpr int XU   = XP / 8;             // 16B chunks per x row (13/25/21)

    // stage W segment (bf16, pre-transposed, padded): linear uint4 copies
    const uint4* __restrict__ wsrc = (const uint4*)(wt_e + WB);
    for (int idx = t; idx < WCH; idx += 256) ((uint4*)lds_w)[idx] = wsrc[idx];

    // stage x rows: per-row uint4 copies from pre-formatted xs
    {
        const int r = t >> 3, j = t & 7;     // 8 threads per row
        const uint4* __restrict__ src = (const uint4*)(xs_seg + (size_t)rid_s[r] * XP);
        uint4* __restrict__ dst = (uint4*)lds_x + r * XU;
        #pragma unroll
        for (int c = j; c < XU; c += 8) dst[c] = src[c];
    }
    __syncthreads();

    // compute: C-tiles round-robin over 4 waves
    const int lane = t & 63, w = t >> 6;
    const int row_l = lane & 15, kg = lane >> 4;
    for (int ct = w; ct < MTL * NT; ct += 4) {
        const int mIdx = ct / NT, nt = ct - mIdx * NT;
        const int mt = mIdx & 1, mch = mIdx >> 1;
        f32x4 acc = {0.f, 0.f, 0.f, 0.f};
        #pragma unroll
        for (int kb = 0; kb < KB; ++kb) {
            const short8 a = *(const short8*)&lds_x[(mt * 16 + row_l) * XP + mch * MI + kb * 32 + kg * 8];
            const short8 b = *(const short8*)&lds_w[(nt * 16 + row_l) * WSTR + kb * 32 + kg * 8];
            acc = __builtin_amdgcn_mfma_f32_16x16x32_bf16(a, b, acc, 0, 0, 0);
        }
        const int o = nt * 16 + row_l;
        #pragma unroll
        for (int jj = 0; jj < 4; ++jj) {
            const int m = mt * 16 + kg * 4 + jj;
            if (m < nrows)
                out[(size_t)rid_s[m] * OUT_SIZE + YOFF + o * D + mch] = acc[jj];
        }
    }
}

__global__ __launch_bounds__(256) void gemm_kernel(
    const unsigned short* __restrict__ xs0, const unsigned short* __restrict__ xs1,
    const unsigned short* __restrict__ xs2, const unsigned short* __restrict__ wt,
    const int* __restrict__ rowids, const int* __restrict__ offsets,
    const int* __restrict__ tileoff, const int* __restrict__ blk2e,
    float* __restrict__ out) {
    // union LDS: seg0 96*104 + 32*104 = 13312 halves (26.6 KB) is the max
    __shared__ __align__(16) unsigned short lds[13312];
    __shared__ int rid_s[RTILE];

    const int t   = threadIdx.x;
    const int seg = blockIdx.x / MAXTILES;
    const int tb  = blockIdx.x - seg * MAXTILES;
    const int e   = blk2e[tb];
    if (e < 0) return;
    const int tile  = tb - tileoff[e];
    const int r0    = offsets[e];
    const int cnt   = offsets[e + 1] - r0;
    const int rbase = r0 + tile * RTILE;
    const int nrows = min(RTILE, cnt - tile * RTILE);
    if (t < RTILE) rid_s[t] = rowids[rbase + min(t, nrows - 1)];  // clamp: ghosts stage real rows
    __syncthreads();

    const unsigned short* wt_e = wt + (size_t)e * WT_ELEM;
    if (seg == 0)
        do_seg<96, 96, 1,   0,     0>(xs0, wt_e, rid_s, nrows, out, lds, lds + 9984, t);
    else if (seg == 1)
        do_seg<64, 64, 3,  96,  9984>(xs1, wt_e, rid_s, nrows, out, lds, lds + 4608, t);
    else
        do_seg<32, 32, 5, 288, 14592>(xs2, wt_e, rid_s, nrows, out, lds, lds + 1280, t);
}

// ---------------- launcher ----------------

extern "C" void kernel_launch(void* const* d_in, const int* in_sizes, int n_in,
                              void* d_out, int out_size, void* d_ws, size_t ws_size,
                              hipStream_t stream) {
    const float* weights = (const float*)d_in[0];   // [64, 14336] f32
    const float* x       = (const float*)d_in[1];   // [16384, 448] f32
    const int*   widx    = (const int*)d_in[2];     // [16384] int32
    float*       out     = (float*)d_out;           // [16384, 448] f32

    char* ws = (char*)d_ws;
    int* hists   = (int*)(ws + 0);                  // 64*64 ints = 16 KB
    int* offsets = (int*)(ws + 16384);              // 65
    int* tileoff = (int*)(ws + 16896);              // 65
    int* blk2e   = (int*)(ws + 17408);              // 576
    int* rowids  = (int*)(ws + 20480);              // 16384 ints
    unsigned short* wt  = (unsigned short*)(ws + 86016);     // 64*15872 halves = 1.94 MB
    unsigned short* xs0 = (unsigned short*)(ws + 4194304);   // 16384*104 halves = 3.25 MB
    unsigned short* xs1 = (unsigned short*)(ws + 7602176);   // 16384*200 halves = 6.25 MB
    unsigned short* xs2 = (unsigned short*)(ws + 14155776);  // 16384*168 halves = 5.25 MB

    combo_kernel  <<<1152, 256, 0, stream>>>(widx, weights, x, hists, wt, xs0, xs1, xs2);
    scatter_kernel<<<64,   256, 0, stream>>>(widx, hists, offsets, tileoff, blk2e, rowids);
    gemm_kernel   <<<3 * MAXTILES, 256, 0, stream>>>(xs0, xs1, xs2, wt,
                                                     rowids, offsets, tileoff, blk2e, out);
}